// Round 3
// baseline (1700.166 us; speedup 1.0000x reference)
//
#include <hip/hip_runtime.h>
#include <hip/hip_bf16.h>

// ---------------------------------------------------------------------------
// SolitonInteractionLayer: fused PDE (sine-Gordon + KdV + Heimburg-Jackson,
// RK4, 3 steps) along T, then out = evolved @ W^T + b via bf16 MFMA GEMM.
//
// PDE: causal stencils only. Dependence depth = 12 rhs evals * <=4 = 48 ->
// tile T with left halo 48. Thread owns NP=8 contiguous t-points in regs;
// chunk halo moves via __shfl_up within the 64-lane wave (wave = d-column).
// Substep loops iterate i DESCENDING (causal -> safe in-place).
//
// R8 (this round):
//  - 512-thr blocks, wave = one d-column -> 8 consecutive d per block.
//    R7's 4-d blocks quartered line locality: FETCH 36->262MB, WRITE
//    37->138MB (cross-XCD partial-line writes). This restores it.
//  - Per-solver halo depth: SG shfls 2, KdV 3, HJ 4 (was always 4) ->
//    25% fewer ds_bpermute ops. Contamination advance per eval <= depth,
//    still <= 48 total -> interior exact.
//  - launch_bounds(512,8): cap VGPR 64 (compiler already chose 64 at NP=8).
//  - GEMM: prefetch depth 1 -> 3. BK 64->32, FOUR LDS buffers (4x32KB),
//    stage tile t+3 after the tile-t barrier, steady vmcnt(8), ONE barrier
//    per K-tile. R7's depth-1 meant the vmcnt wait covered only ~1 compute
//    phase (~600cy) < HBM latency (~900cy) -> stall at every K-step top.
// ---------------------------------------------------------------------------

typedef __bf16 bf16x8 __attribute__((ext_vector_type(8)));
typedef __bf16 bf16x4 __attribute__((ext_vector_type(4)));
typedef float  floatx4 __attribute__((ext_vector_type(4)));

#define T_DIM 4096
#define D_DIM 1024
#define NP    8       // t-points per thread chunk
#define HALO  48      // 6 chunks
#define NCH   64      // chunks per d-column (one 64-lane wave)
#define TINT  (NCH * NP - HALO)   // 464 interior t per block
#define NTT   9       // ceil(4096/464)

__device__ __forceinline__ float sg_rhs(float c, float m1, float m2, float vv) {
  float dxx = fmaf(-2.f, m1, c) + m2;           // u - 2u1 + u2   (C2 = 1)
  return dxx - __sinf(c) - 0.5f * vv;
}
__device__ __forceinline__ float kdv_rhs(float c, float m1, float m2, float m3) {
  float dxu = c - m1;
  float dx3 = fmaf(-3.f, m1, c) + fmaf(3.f, m2, -m3);   // u -3u1 +3u2 -u3
  return fmaf(-6.f * c, dxu, -dx3 - 0.5f * c);
}
// HJ with g-reuse: k = (g[i] - g[i-1]) - dxxxx - 0.5 v
__device__ __forceinline__ float hj_rhs2(float c, float m1, float m2, float m3,
                                         float m4, float dg, float vv) {
  float d4 = fmaf(-4.f, m3, fmaf(6.f, m2, fmaf(-4.f, m1, c))) + m4;  // dxxxx
  return (dg - d4) - 0.5f * vv;
}
__device__ __forceinline__ float hj_g(float c, float m1) {
  return (fmaf(c, c, c) + 1.f) * (c - m1);      // (1+u+u^2)*dx(u)
}

// stencil access with register halo (compile-time idx after unroll):
// i=-1 -> hl[3], -2 -> hl[2], -3 -> hl[1], -4 -> hl[0]
#define AT(F, i) (((i) >= 0) ? F[(i)] : hl[4 + (i)])
// pull neighbor chunk's top values (lane tr-1). tr==0 self-receives:
// contamination advances <= depth per eval, total <= 48 = HALO -> interior
// (tr >= 6) exact.
#define XCHG4(F) do { \
    hl[0] = __shfl_up(F[NP - 4], 1, 64); \
    hl[1] = __shfl_up(F[NP - 3], 1, 64); \
    hl[2] = __shfl_up(F[NP - 2], 1, 64); \
    hl[3] = __shfl_up(F[NP - 1], 1, 64); \
  } while (0)
#define XCHG3(F) do { \
    hl[1] = __shfl_up(F[NP - 3], 1, 64); \
    hl[2] = __shfl_up(F[NP - 2], 1, 64); \
    hl[3] = __shfl_up(F[NP - 1], 1, 64); \
  } while (0)
#define XCHG2(F) do { \
    hl[2] = __shfl_up(F[NP - 2], 1, 64); \
    hl[3] = __shfl_up(F[NP - 1], 1, 64); \
  } while (0)

__global__ __launch_bounds__(512, 8)
void pde_kernel(const float* __restrict__ x, const float* __restrict__ mix,
                __bf16* __restrict__ evout) {
  const int tid  = threadIdx.x;
  const int tr   = tid & 63;       // chunk index within d-column (= lane)
  const int wid  = tid >> 6;       // 0..7 = d-column (one wave each)
  const int d    = blockIdx.y * 8 + wid;
  const int b    = blockIdx.z;
  const int t0   = blockIdx.x * TINT;
  const int tb   = t0 - HALO + tr * NP;   // t of reg[0]

  // softmax(solver_mix) per-thread (3 elements)
  float s0 = mix[0], s1 = mix[1], s2 = mix[2];
  float mxv = fmaxf(s0, fmaxf(s1, s2));
  float e0 = __expf(s0 - mxv), e1 = __expf(s1 - mxv), e2 = __expf(s2 - mxv);
  float inv = 1.f / (e0 + e1 + e2);
  float w0 = e0 * inv, w1 = e1 * inv, w2 = e2 * inv;

  const float* xp = x + ((size_t)b * T_DIM) * D_DIM + d;

  float u0[NP], u[NP], v[NP], ut[NP], vt[NP], au[NP], av[NP], ev[NP], hl[4];

  #pragma unroll
  for (int j = 0; j < NP; ++j) {
    int t = tb + j;
    float xv = (t >= 0 && t < T_DIM) ? xp[(size_t)t * D_DIM] : 0.f;
    // fast tanh: 2*tanh(x) = 2 - 4/(e^{2x}+1); clamp avoids inf/inf
    float xc = fminf(fmaxf(xv, -9.f), 9.f);
    float ex = __expf(2.f * xc);
    u0[j] = 2.f - 4.f * __builtin_amdgcn_rcpf(ex + 1.f);
  }

  // ---------------- sine-Gordon (2nd order, dt = 0.05) ----------------
  {
    const float dt = 0.05f, h = 0.025f, w6 = dt * (1.f / 6.f);
    #pragma unroll
    for (int j = 0; j < NP; ++j) { u[j] = u0[j]; v[j] = 0.f; }
    #pragma unroll 1
    for (int s = 0; s < 3; ++s) {
      XCHG2(u);
      #pragma unroll
      for (int i = NP - 1; i >= 0; --i) {            // k1
        float k = sg_rhs(u[i], AT(u, i - 1), AT(u, i - 2), v[i]);
        au[i] = v[i]; av[i] = k;
        ut[i] = fmaf(h, v[i], u[i]);
        vt[i] = fmaf(h, k, v[i]);
      }
      XCHG2(ut);
      #pragma unroll
      for (int i = NP - 1; i >= 0; --i) {            // k2
        float k = sg_rhs(ut[i], AT(ut, i - 1), AT(ut, i - 2), vt[i]);
        au[i] = fmaf(2.f, vt[i], au[i]); av[i] = fmaf(2.f, k, av[i]);
        float nu = fmaf(h, vt[i], u[i]);             // u + h*k2u (k2u = old vt)
        vt[i] = fmaf(h, k, v[i]);
        ut[i] = nu;
      }
      XCHG2(ut);
      #pragma unroll
      for (int i = NP - 1; i >= 0; --i) {            // k3
        float k = sg_rhs(ut[i], AT(ut, i - 1), AT(ut, i - 2), vt[i]);
        au[i] = fmaf(2.f, vt[i], au[i]); av[i] = fmaf(2.f, k, av[i]);
        float nu = fmaf(dt, vt[i], u[i]);
        vt[i] = fmaf(dt, k, v[i]);
        ut[i] = nu;
      }
      XCHG2(ut);
      #pragma unroll
      for (int i = NP - 1; i >= 0; --i) {            // k4 + combine
        float k = sg_rhs(ut[i], AT(ut, i - 1), AT(ut, i - 2), vt[i]);
        au[i] += vt[i]; av[i] += k;
        u[i] = fmaf(w6, au[i], u[i]);
        v[i] = fmaf(w6, av[i], v[i]);
      }
    }
    #pragma unroll
    for (int j = 0; j < NP; ++j) ev[j] = w0 * u[j];
  }

  // ---------------- KdV (1st order, dt = 0.025) ----------------
  {
    const float dt = 0.025f, h = 0.0125f, w6 = dt * (1.f / 6.f);
    #pragma unroll
    for (int j = 0; j < NP; ++j) u[j] = u0[j];
    #pragma unroll 1
    for (int s = 0; s < 3; ++s) {
      XCHG3(u);
      #pragma unroll
      for (int i = NP - 1; i >= 0; --i) {            // k1
        float k = kdv_rhs(u[i], AT(u, i - 1), AT(u, i - 2), AT(u, i - 3));
        au[i] = k;
        ut[i] = fmaf(h, k, u[i]);
      }
      XCHG3(ut);
      #pragma unroll
      for (int i = NP - 1; i >= 0; --i) {            // k2
        float k = kdv_rhs(ut[i], AT(ut, i - 1), AT(ut, i - 2), AT(ut, i - 3));
        au[i] = fmaf(2.f, k, au[i]);
        ut[i] = fmaf(h, k, u[i]);
      }
      XCHG3(ut);
      #pragma unroll
      for (int i = NP - 1; i >= 0; --i) {            // k3
        float k = kdv_rhs(ut[i], AT(ut, i - 1), AT(ut, i - 2), AT(ut, i - 3));
        au[i] = fmaf(2.f, k, au[i]);
        ut[i] = fmaf(dt, k, u[i]);
      }
      XCHG3(ut);
      #pragma unroll
      for (int i = NP - 1; i >= 0; --i) {            // k4 + combine
        float k = kdv_rhs(ut[i], AT(ut, i - 1), AT(ut, i - 2), AT(ut, i - 3));
        u[i] = fmaf(w6, au[i] + k, u[i]);
      }
    }
    #pragma unroll
    for (int j = 0; j < NP; ++j) ev[j] = fmaf(w1, u[j], ev[j]);
  }

  // ---------------- Heimburg-Jackson (2nd order, dt = 0.025) ----------------
  {
    const float dt = 0.025f, h = 0.0125f, w6 = dt * (1.f / 6.f);
    float g[NP], gB;
    // per-substep: XCHG4(SRC); precompute g[] (old values); then descending
    // in-place update. g uses only SRC[i], SRC[i-1] -> safe before update.
#define HJ_GPRE(SRC) do {                                                  \
      gB = hj_g(hl[3], hl[2]);                                             \
      _Pragma("unroll")                                                    \
      for (int i_ = 0; i_ < NP; ++i_)                                      \
        g[i_] = hj_g(SRC[i_], AT(SRC, i_ - 1));                           \
    } while (0)
#define DG(i) ((i) ? (g[(i) - 1]) : gB)

    #pragma unroll
    for (int j = 0; j < NP; ++j) { u[j] = u0[j]; v[j] = 0.f; }
    #pragma unroll 1
    for (int s = 0; s < 3; ++s) {
      XCHG4(u);
      HJ_GPRE(u);
      #pragma unroll
      for (int i = NP - 1; i >= 0; --i) {            // k1
        float k = hj_rhs2(u[i], AT(u, i - 1), AT(u, i - 2), AT(u, i - 3),
                          AT(u, i - 4), g[i] - DG(i), v[i]);
        au[i] = v[i]; av[i] = k;
        ut[i] = fmaf(h, v[i], u[i]);
        vt[i] = fmaf(h, k, v[i]);
      }
      XCHG4(ut);
      HJ_GPRE(ut);
      #pragma unroll
      for (int i = NP - 1; i >= 0; --i) {            // k2
        float k = hj_rhs2(ut[i], AT(ut, i - 1), AT(ut, i - 2), AT(ut, i - 3),
                          AT(ut, i - 4), g[i] - DG(i), vt[i]);
        au[i] = fmaf(2.f, vt[i], au[i]); av[i] = fmaf(2.f, k, av[i]);
        float nu = fmaf(h, vt[i], u[i]);
        vt[i] = fmaf(h, k, v[i]);
        ut[i] = nu;
      }
      XCHG4(ut);
      HJ_GPRE(ut);
      #pragma unroll
      for (int i = NP - 1; i >= 0; --i) {            // k3
        float k = hj_rhs2(ut[i], AT(ut, i - 1), AT(ut, i - 2), AT(ut, i - 3),
                          AT(ut, i - 4), g[i] - DG(i), vt[i]);
        au[i] = fmaf(2.f, vt[i], au[i]); av[i] = fmaf(2.f, k, av[i]);
        float nu = fmaf(dt, vt[i], u[i]);
        vt[i] = fmaf(dt, k, v[i]);
        ut[i] = nu;
      }
      XCHG4(ut);
      HJ_GPRE(ut);
      #pragma unroll
      for (int i = NP - 1; i >= 0; --i) {            // k4 + combine
        float k = hj_rhs2(ut[i], AT(ut, i - 1), AT(ut, i - 2), AT(ut, i - 3),
                          AT(ut, i - 4), g[i] - DG(i), vt[i]);
        au[i] += vt[i]; av[i] += k;
        u[i] = fmaf(w6, au[i], u[i]);
        v[i] = fmaf(w6, av[i], v[i]);
      }
    }
#undef HJ_GPRE
#undef DG
    #pragma unroll
    for (int j = 0; j < NP; ++j) ev[j] = fmaf(w2, u[j], ev[j]);
  }

  // store interior chunks (tr >= HALO/NP) as bf16 A-matrix [b*T+t][d]
  if (tr >= HALO / NP) {
    #pragma unroll
    for (int j = 0; j < NP; ++j) {
      int t = tb + j;
      if (t < T_DIM)
        evout[((size_t)(b * T_DIM + t)) * D_DIM + d] = (__bf16)ev[j];
    }
  }
}

// ---------------------------------------------------------------------------
// W (fp32, [E][D]) -> bf16
// ---------------------------------------------------------------------------
__global__ __launch_bounds__(256)
void convert_w(const float* __restrict__ W, __bf16* __restrict__ Wb) {
  int i = blockIdx.x * 256 + threadIdx.x;   // over D*D/4
  float4 f = ((const float4*)W)[i];
  bf16x4 o = {(__bf16)f.x, (__bf16)f.y, (__bf16)f.z, (__bf16)f.w};
  ((bf16x4*)Wb)[i] = o;
}

// ---------------------------------------------------------------------------
// GEMM: out[m][n] = sum_k A[m][k] * Wb[n][k] + bias[n]
// M=16384, N=1024, K=1024.
//
// R8: 256x256 block tile, BK=32, 512 threads / 8 waves (2Mx4N, wave tile
// 128x64, acc[8][4]), mfma_f32_16x16x32_bf16. FOUR LDS buffers (4 x
// (A 16KB + B 16KB) = 128 KiB) -> prefetch depth 3 K-tiles (~3 compute
// phases > HBM latency). Per tile: vmcnt(8) [2 newer tiles x 4 loads
// outstanding] + s_barrier; STAGE(t+3) AFTER the barrier (its target buf's
// readers all passed the barrier: a wave's ds_reads complete before its own
// MFMA consumes, which precedes 3 later barriers -> no end-of-read barrier
// needed at depth>=2). 32 tiles, tail peeled with vmcnt(8/4/0).
// LDS swizzle (row length 64B = 4 granules): slot = granule ^ ((row>>1)&3)
// -> every bank serves exactly 2 lanes of a b128 read (2-way = free);
// inverse-swizzle on the global source (both-sides-or-neither).
// Grid (64,4): same-A blocks 64 apart (64%8==0 -> same XCD L2).
// ---------------------------------------------------------------------------
#define GK   1024

__global__ __launch_bounds__(512, 1)
void gemm_kernel(const __bf16* __restrict__ A, const __bf16* __restrict__ Bw,
                 const float* __restrict__ bias, float* __restrict__ out) {
  __shared__ __align__(16) __bf16 As[4][256 * 32];   // 4 x 16 KB
  __shared__ __align__(16) __bf16 Bs[4][256 * 32];   // 4 x 16 KB

  const int tid  = threadIdx.x;
  const int lane = tid & 63;
  const int wid  = tid >> 6;           // 0..7
  const int m0   = blockIdx.x * 256;
  const int n0   = blockIdx.y * 256;
  const int wm   = (wid >> 2) * 128;   // 0 or 128
  const int wn   = (wid & 3) * 64;     // 0..192
  const int l15  = lane & 15;
  const int quad = lane >> 4;          // K-granule 0..3 (K=32 = 4 x 8 elems)

  // staging: one global_load_lds = 64 lanes x 16B = 16 rows x 64B.
  // lane -> LDS (row = lane>>2, slot = lane&3); must FETCH global granule
  // slot ^ ((row>>1)&3)  (inverse of the read-side swizzle).
  const int srow = lane >> 2;                      // 0..15
  const int sgr  = (lane & 3) ^ ((lane >> 3) & 3); // swizzled global granule

  // wave w stages rows [w*32, w*32+32) of both tiles (2+2 loads)
  const __bf16* aBase = A  + (size_t)(m0 + wid * 32 + srow) * GK + sgr * 8;
  const __bf16* bBase = Bw + (size_t)(n0 + wid * 32 + srow) * GK + sgr * 8;

#define STAGE(tt) do {                                                        \
    int _bf = (tt) & 3, _kt = (tt) * 32;                                      \
    _Pragma("unroll")                                                         \
    for (int p = 0; p < 2; ++p)                                               \
      __builtin_amdgcn_global_load_lds(                                       \
          (const uint32_t*)(aBase + (size_t)(p * 16) * GK + _kt),             \
          (uint32_t*)&As[_bf][(wid * 32 + p * 16) * 32], 16, 0, 0);           \
    _Pragma("unroll")                                                         \
    for (int p = 0; p < 2; ++p)                                               \
      __builtin_amdgcn_global_load_lds(                                       \
          (const uint32_t*)(bBase + (size_t)(p * 16) * GK + _kt),             \
          (uint32_t*)&Bs[_bf][(wid * 32 + p * 16) * 32], 16, 0, 0);           \
  } while (0)

#define COMPUTE(bi) do {                                                      \
    const __bf16* as_ = As[bi];                                               \
    const __bf16* bs_ = Bs[bi];                                               \
    bf16x8 af[8], bfr[4];                                                     \
    _Pragma("unroll")                                                         \
    for (int i = 0; i < 8; ++i) {                                             \
      int ra = wm + i * 16 + l15;                                             \
      af[i] = *(const bf16x8*)(&as_[ra * 32 + ((quad ^ ((ra >> 1) & 3)) * 8)]);\
    }                                                                         \
    _Pragma("unroll")                                                         \
    for (int j = 0; j < 4; ++j) {                                             \
      int rb = wn + j * 16 + l15;                                             \
      bfr[j] = *(const bf16x8*)(&bs_[rb * 32 + ((quad ^ ((rb >> 1) & 3)) * 8)]);\
    }                                                                         \
    _Pragma("unroll")                                                         \
    for (int i = 0; i < 8; ++i)                                               \
      _Pragma("unroll")                                                       \
      for (int j = 0; j < 4; ++j)                                             \
        acc[i][j] = __builtin_amdgcn_mfma_f32_16x16x32_bf16(                  \
            af[i], bfr[j], acc[i][j], 0, 0, 0);                               \
  } while (0)

#define TILE_BARRIER(vm) do {                                                 \
    asm volatile("s_waitcnt vmcnt(" #vm ")" ::: "memory");                    \
    __builtin_amdgcn_sched_barrier(0);                                        \
    __builtin_amdgcn_s_barrier();                                             \
    __builtin_amdgcn_sched_barrier(0);                                        \
  } while (0)

  floatx4 acc[8][4] = {};

  STAGE(0); STAGE(1); STAGE(2);             // depth-3 prologue (12 loads)

  #pragma unroll 1
  for (int t = 0; t < 29; ++t) {            // steady state: stage t+3
    TILE_BARRIER(8);                        // tile t landed (2 newer in air)
    STAGE(t + 3);
    COMPUTE(t & 3);
  }
  TILE_BARRIER(8); COMPUTE(1);              // t=29 (29&3==1), no stage left
  TILE_BARRIER(4); COMPUTE(2);              // t=30
  TILE_BARRIER(0); COMPUTE(3);              // t=31
#undef STAGE
#undef COMPUTE
#undef TILE_BARRIER

  // epilogue: D[m=quad*4+r][n=l15] per 16x16 tile; add bias
  #pragma unroll
  for (int j = 0; j < 4; ++j) {
    int n = n0 + wn + j * 16 + l15;
    float bv = bias[n];
    #pragma unroll
    for (int i = 0; i < 8; ++i) {
      int mb = m0 + wm + i * 16 + quad * 4;
      #pragma unroll
      for (int r = 0; r < 4; ++r)
        out[(size_t)(mb + r) * 1024 + n] = acc[i][j][r] + bv;
    }
  }
}

// ---------------------------------------------------------------------------
extern "C" void kernel_launch(void* const* d_in, const int* in_sizes, int n_in,
                              void* d_out, int out_size, void* d_ws, size_t ws_size,
                              hipStream_t stream) {
  const float* x    = (const float*)d_in[0];
  const float* mix  = (const float*)d_in[1];
  const float* W    = (const float*)d_in[2];
  const float* bias = (const float*)d_in[3];
  float* out = (float*)d_out;

  __bf16* ev = (__bf16*)d_ws;                                     // 32 MiB
  __bf16* Wb = (__bf16*)((char*)d_ws + (size_t)32 * 1024 * 1024); // 2 MiB

  convert_w<<<dim3((D_DIM * D_DIM / 4) / 256), 256, 0, stream>>>(W, Wb);
  pde_kernel<<<dim3(NTT, D_DIM / 8, 4), 512, 0, stream>>>(x, mix, ev);
  gemm_kernel<<<dim3(16384 / 256, 1024 / 256), 512, 0, stream>>>(ev, Wb, bias, out);
}

// Round 4
// 324.675 us; speedup vs baseline: 5.2365x; 5.2365x over previous
//
#include <hip/hip_runtime.h>
#include <hip/hip_bf16.h>

// ---------------------------------------------------------------------------
// SolitonInteractionLayer: fused PDE (sine-Gordon + KdV + Heimburg-Jackson,
// RK4, 3 steps) along T, then out = evolved @ W^T + b via bf16 MFMA GEMM.
//
// PDE: causal stencils only. Dependence depth = 12 rhs evals * <=4 = 48 ->
// tile T with left halo 48. Thread owns NP=8 contiguous t-points in regs;
// chunk halo moves via __shfl_up within the 64-lane wave (wave = d-column).
// Substep loops iterate i DESCENDING (causal -> safe in-place).
//
// VGPR history (do NOT tighten launch_bounds):
//   (256,2) VGPR128 218us | (256,4) VGPR64 218us | (512,8) VGPR32 SPILL
//   6.5GB scratch traffic, 1620us. Kernel needs ~70 live floats; cap >= 128.
// R9: revert to (512,4) — cap 128, compiler settles at 64, no spill, up to
// 8 waves/SIMD still possible (LDS=0). Occupancy is NOT the lever here
// (issue-bound at ~75% VALUBusy); spill avoidance dominates everything.
// ---------------------------------------------------------------------------

typedef __bf16 bf16x8 __attribute__((ext_vector_type(8)));
typedef __bf16 bf16x4 __attribute__((ext_vector_type(4)));
typedef float  floatx4 __attribute__((ext_vector_type(4)));

#define T_DIM 4096
#define D_DIM 1024
#define NP    8       // t-points per thread chunk
#define HALO  48      // 6 chunks
#define NCH   64      // chunks per d-column (one 64-lane wave)
#define TINT  (NCH * NP - HALO)   // 464 interior t per block
#define NTT   9       // ceil(4096/464)

__device__ __forceinline__ float sg_rhs(float c, float m1, float m2, float vv) {
  float dxx = fmaf(-2.f, m1, c) + m2;           // u - 2u1 + u2   (C2 = 1)
  return dxx - __sinf(c) - 0.5f * vv;
}
__device__ __forceinline__ float kdv_rhs(float c, float m1, float m2, float m3) {
  float dxu = c - m1;
  float dx3 = fmaf(-3.f, m1, c) + fmaf(3.f, m2, -m3);   // u -3u1 +3u2 -u3
  return fmaf(-6.f * c, dxu, -dx3 - 0.5f * c);
}
// HJ with g-reuse: k = (g[i] - g[i-1]) - dxxxx - 0.5 v
__device__ __forceinline__ float hj_rhs2(float c, float m1, float m2, float m3,
                                         float m4, float dg, float vv) {
  float d4 = fmaf(-4.f, m3, fmaf(6.f, m2, fmaf(-4.f, m1, c))) + m4;  // dxxxx
  return (dg - d4) - 0.5f * vv;
}
__device__ __forceinline__ float hj_g(float c, float m1) {
  return (fmaf(c, c, c) + 1.f) * (c - m1);      // (1+u+u^2)*dx(u)
}

// stencil access with register halo (compile-time idx after unroll):
// i=-1 -> hl[3], -2 -> hl[2], -3 -> hl[1], -4 -> hl[0]
#define AT(F, i) (((i) >= 0) ? F[(i)] : hl[4 + (i)])
// pull neighbor chunk's top values (lane tr-1). tr==0 self-receives:
// contamination advances <= depth per eval; per-solver totals (12 evals x
// depth: SG 24, KdV 36, HJ 48) all <= HALO=48 -> interior (tr>=6) exact.
#define XCHG4(F) do { \
    hl[0] = __shfl_up(F[NP - 4], 1, 64); \
    hl[1] = __shfl_up(F[NP - 3], 1, 64); \
    hl[2] = __shfl_up(F[NP - 2], 1, 64); \
    hl[3] = __shfl_up(F[NP - 1], 1, 64); \
  } while (0)
#define XCHG3(F) do { \
    hl[1] = __shfl_up(F[NP - 3], 1, 64); \
    hl[2] = __shfl_up(F[NP - 2], 1, 64); \
    hl[3] = __shfl_up(F[NP - 1], 1, 64); \
  } while (0)
#define XCHG2(F) do { \
    hl[2] = __shfl_up(F[NP - 2], 1, 64); \
    hl[3] = __shfl_up(F[NP - 1], 1, 64); \
  } while (0)

__global__ __launch_bounds__(512, 4)
void pde_kernel(const float* __restrict__ x, const float* __restrict__ mix,
                __bf16* __restrict__ evout) {
  const int tid  = threadIdx.x;
  const int tr   = tid & 63;       // chunk index within d-column (= lane)
  const int wid  = tid >> 6;       // 0..7 = d-column (one wave each)
  const int d    = blockIdx.y * 8 + wid;
  const int b    = blockIdx.z;
  const int t0   = blockIdx.x * TINT;
  const int tb   = t0 - HALO + tr * NP;   // t of reg[0]

  // softmax(solver_mix) per-thread (3 elements)
  float s0 = mix[0], s1 = mix[1], s2 = mix[2];
  float mxv = fmaxf(s0, fmaxf(s1, s2));
  float e0 = __expf(s0 - mxv), e1 = __expf(s1 - mxv), e2 = __expf(s2 - mxv);
  float inv = 1.f / (e0 + e1 + e2);
  float w0 = e0 * inv, w1 = e1 * inv, w2 = e2 * inv;

  const float* xp = x + ((size_t)b * T_DIM) * D_DIM + d;

  float u0[NP], u[NP], v[NP], ut[NP], vt[NP], au[NP], av[NP], ev[NP], hl[4];

  #pragma unroll
  for (int j = 0; j < NP; ++j) {
    int t = tb + j;
    float xv = (t >= 0 && t < T_DIM) ? xp[(size_t)t * D_DIM] : 0.f;
    // fast tanh: 2*tanh(x) = 2 - 4/(e^{2x}+1); clamp avoids inf/inf
    float xc = fminf(fmaxf(xv, -9.f), 9.f);
    float ex = __expf(2.f * xc);
    u0[j] = 2.f - 4.f * __builtin_amdgcn_rcpf(ex + 1.f);
  }

  // ---------------- sine-Gordon (2nd order, dt = 0.05) ----------------
  {
    const float dt = 0.05f, h = 0.025f, w6 = dt * (1.f / 6.f);
    #pragma unroll
    for (int j = 0; j < NP; ++j) { u[j] = u0[j]; v[j] = 0.f; }
    #pragma unroll 1
    for (int s = 0; s < 3; ++s) {
      XCHG2(u);
      #pragma unroll
      for (int i = NP - 1; i >= 0; --i) {            // k1
        float k = sg_rhs(u[i], AT(u, i - 1), AT(u, i - 2), v[i]);
        au[i] = v[i]; av[i] = k;
        ut[i] = fmaf(h, v[i], u[i]);
        vt[i] = fmaf(h, k, v[i]);
      }
      XCHG2(ut);
      #pragma unroll
      for (int i = NP - 1; i >= 0; --i) {            // k2
        float k = sg_rhs(ut[i], AT(ut, i - 1), AT(ut, i - 2), vt[i]);
        au[i] = fmaf(2.f, vt[i], au[i]); av[i] = fmaf(2.f, k, av[i]);
        float nu = fmaf(h, vt[i], u[i]);             // u + h*k2u (k2u = old vt)
        vt[i] = fmaf(h, k, v[i]);
        ut[i] = nu;
      }
      XCHG2(ut);
      #pragma unroll
      for (int i = NP - 1; i >= 0; --i) {            // k3
        float k = sg_rhs(ut[i], AT(ut, i - 1), AT(ut, i - 2), vt[i]);
        au[i] = fmaf(2.f, vt[i], au[i]); av[i] = fmaf(2.f, k, av[i]);
        float nu = fmaf(dt, vt[i], u[i]);
        vt[i] = fmaf(dt, k, v[i]);
        ut[i] = nu;
      }
      XCHG2(ut);
      #pragma unroll
      for (int i = NP - 1; i >= 0; --i) {            // k4 + combine
        float k = sg_rhs(ut[i], AT(ut, i - 1), AT(ut, i - 2), vt[i]);
        au[i] += vt[i]; av[i] += k;
        u[i] = fmaf(w6, au[i], u[i]);
        v[i] = fmaf(w6, av[i], v[i]);
      }
    }
    #pragma unroll
    for (int j = 0; j < NP; ++j) ev[j] = w0 * u[j];
  }

  // ---------------- KdV (1st order, dt = 0.025) ----------------
  {
    const float dt = 0.025f, h = 0.0125f, w6 = dt * (1.f / 6.f);
    #pragma unroll
    for (int j = 0; j < NP; ++j) u[j] = u0[j];
    #pragma unroll 1
    for (int s = 0; s < 3; ++s) {
      XCHG3(u);
      #pragma unroll
      for (int i = NP - 1; i >= 0; --i) {            // k1
        float k = kdv_rhs(u[i], AT(u, i - 1), AT(u, i - 2), AT(u, i - 3));
        au[i] = k;
        ut[i] = fmaf(h, k, u[i]);
      }
      XCHG3(ut);
      #pragma unroll
      for (int i = NP - 1; i >= 0; --i) {            // k2
        float k = kdv_rhs(ut[i], AT(ut, i - 1), AT(ut, i - 2), AT(ut, i - 3));
        au[i] = fmaf(2.f, k, au[i]);
        ut[i] = fmaf(h, k, u[i]);
      }
      XCHG3(ut);
      #pragma unroll
      for (int i = NP - 1; i >= 0; --i) {            // k3
        float k = kdv_rhs(ut[i], AT(ut, i - 1), AT(ut, i - 2), AT(ut, i - 3));
        au[i] = fmaf(2.f, k, au[i]);
        ut[i] = fmaf(dt, k, u[i]);
      }
      XCHG3(ut);
      #pragma unroll
      for (int i = NP - 1; i >= 0; --i) {            // k4 + combine
        float k = kdv_rhs(ut[i], AT(ut, i - 1), AT(ut, i - 2), AT(ut, i - 3));
        u[i] = fmaf(w6, au[i] + k, u[i]);
      }
    }
    #pragma unroll
    for (int j = 0; j < NP; ++j) ev[j] = fmaf(w1, u[j], ev[j]);
  }

  // ---------------- Heimburg-Jackson (2nd order, dt = 0.025) ----------------
  {
    const float dt = 0.025f, h = 0.0125f, w6 = dt * (1.f / 6.f);
    float g[NP], gB;
    // per-substep: XCHG4(SRC); precompute g[] (old values); then descending
    // in-place update. g uses only SRC[i], SRC[i-1] -> safe before update.
#define HJ_GPRE(SRC) do {                                                  \
      gB = hj_g(hl[3], hl[2]);                                             \
      _Pragma("unroll")                                                    \
      for (int i_ = 0; i_ < NP; ++i_)                                      \
        g[i_] = hj_g(SRC[i_], AT(SRC, i_ - 1));                           \
    } while (0)
#define DG(i) ((i) ? (g[(i) - 1]) : gB)

    #pragma unroll
    for (int j = 0; j < NP; ++j) { u[j] = u0[j]; v[j] = 0.f; }
    #pragma unroll 1
    for (int s = 0; s < 3; ++s) {
      XCHG4(u);
      HJ_GPRE(u);
      #pragma unroll
      for (int i = NP - 1; i >= 0; --i) {            // k1
        float k = hj_rhs2(u[i], AT(u, i - 1), AT(u, i - 2), AT(u, i - 3),
                          AT(u, i - 4), g[i] - DG(i), v[i]);
        au[i] = v[i]; av[i] = k;
        ut[i] = fmaf(h, v[i], u[i]);
        vt[i] = fmaf(h, k, v[i]);
      }
      XCHG4(ut);
      HJ_GPRE(ut);
      #pragma unroll
      for (int i = NP - 1; i >= 0; --i) {            // k2
        float k = hj_rhs2(ut[i], AT(ut, i - 1), AT(ut, i - 2), AT(ut, i - 3),
                          AT(ut, i - 4), g[i] - DG(i), vt[i]);
        au[i] = fmaf(2.f, vt[i], au[i]); av[i] = fmaf(2.f, k, av[i]);
        float nu = fmaf(h, vt[i], u[i]);
        vt[i] = fmaf(h, k, v[i]);
        ut[i] = nu;
      }
      XCHG4(ut);
      HJ_GPRE(ut);
      #pragma unroll
      for (int i = NP - 1; i >= 0; --i) {            // k3
        float k = hj_rhs2(ut[i], AT(ut, i - 1), AT(ut, i - 2), AT(ut, i - 3),
                          AT(ut, i - 4), g[i] - DG(i), vt[i]);
        au[i] = fmaf(2.f, vt[i], au[i]); av[i] = fmaf(2.f, k, av[i]);
        float nu = fmaf(dt, vt[i], u[i]);
        vt[i] = fmaf(dt, k, v[i]);
        ut[i] = nu;
      }
      XCHG4(ut);
      HJ_GPRE(ut);
      #pragma unroll
      for (int i = NP - 1; i >= 0; --i) {            // k4 + combine
        float k = hj_rhs2(ut[i], AT(ut, i - 1), AT(ut, i - 2), AT(ut, i - 3),
                          AT(ut, i - 4), g[i] - DG(i), vt[i]);
        au[i] += vt[i]; av[i] += k;
        u[i] = fmaf(w6, au[i], u[i]);
        v[i] = fmaf(w6, av[i], v[i]);
      }
    }
#undef HJ_GPRE
#undef DG
    #pragma unroll
    for (int j = 0; j < NP; ++j) ev[j] = fmaf(w2, u[j], ev[j]);
  }

  // store interior chunks (tr >= HALO/NP) as bf16 A-matrix [b*T+t][d]
  if (tr >= HALO / NP) {
    #pragma unroll
    for (int j = 0; j < NP; ++j) {
      int t = tb + j;
      if (t < T_DIM)
        evout[((size_t)(b * T_DIM + t)) * D_DIM + d] = (__bf16)ev[j];
    }
  }
}

// ---------------------------------------------------------------------------
// W (fp32, [E][D]) -> bf16
// ---------------------------------------------------------------------------
__global__ __launch_bounds__(256)
void convert_w(const float* __restrict__ W, __bf16* __restrict__ Wb) {
  int i = blockIdx.x * 256 + threadIdx.x;   // over D*D/4
  float4 f = ((const float4*)W)[i];
  bf16x4 o = {(__bf16)f.x, (__bf16)f.y, (__bf16)f.z, (__bf16)f.w};
  ((bf16x4*)Wb)[i] = o;
}

// ---------------------------------------------------------------------------
// GEMM: out[m][n] = sum_k A[m][k] * Wb[n][k] + bias[n]
// M=16384, N=1024, K=1024.
//
// R8 GEMM (unchanged): 256x256 block tile, BK=32, 512 threads / 8 waves
// (2Mx4N, wave tile 128x64, acc[8][4]), mfma_f32_16x16x32_bf16. FOUR LDS
// buffers (128 KiB) -> prefetch depth 3 K-tiles. Per tile: vmcnt(8) +
// s_barrier; STAGE(t+3) AFTER the barrier. Tail peeled vmcnt(8/4/0).
// LDS swizzle: slot = granule ^ ((row>>1)&3), inverse on global source.
// ---------------------------------------------------------------------------
#define GK   1024

__global__ __launch_bounds__(512, 1)
void gemm_kernel(const __bf16* __restrict__ A, const __bf16* __restrict__ Bw,
                 const float* __restrict__ bias, float* __restrict__ out) {
  __shared__ __align__(16) __bf16 As[4][256 * 32];   // 4 x 16 KB
  __shared__ __align__(16) __bf16 Bs[4][256 * 32];   // 4 x 16 KB

  const int tid  = threadIdx.x;
  const int lane = tid & 63;
  const int wid  = tid >> 6;           // 0..7
  const int m0   = blockIdx.x * 256;
  const int n0   = blockIdx.y * 256;
  const int wm   = (wid >> 2) * 128;   // 0 or 128
  const int wn   = (wid & 3) * 64;     // 0..192
  const int l15  = lane & 15;
  const int quad = lane >> 4;          // K-granule 0..3 (K=32 = 4 x 8 elems)

  // staging: one global_load_lds = 64 lanes x 16B = 16 rows x 64B.
  // lane -> LDS (row = lane>>2, slot = lane&3); must FETCH global granule
  // slot ^ ((row>>1)&3)  (inverse of the read-side swizzle).
  const int srow = lane >> 2;                      // 0..15
  const int sgr  = (lane & 3) ^ ((lane >> 3) & 3); // swizzled global granule

  // wave w stages rows [w*32, w*32+32) of both tiles (2+2 loads)
  const __bf16* aBase = A  + (size_t)(m0 + wid * 32 + srow) * GK + sgr * 8;
  const __bf16* bBase = Bw + (size_t)(n0 + wid * 32 + srow) * GK + sgr * 8;

#define STAGE(tt) do {                                                        \
    int _bf = (tt) & 3, _kt = (tt) * 32;                                      \
    _Pragma("unroll")                                                         \
    for (int p = 0; p < 2; ++p)                                               \
      __builtin_amdgcn_global_load_lds(                                       \
          (const uint32_t*)(aBase + (size_t)(p * 16) * GK + _kt),             \
          (uint32_t*)&As[_bf][(wid * 32 + p * 16) * 32], 16, 0, 0);           \
    _Pragma("unroll")                                                         \
    for (int p = 0; p < 2; ++p)                                               \
      __builtin_amdgcn_global_load_lds(                                       \
          (const uint32_t*)(bBase + (size_t)(p * 16) * GK + _kt),             \
          (uint32_t*)&Bs[_bf][(wid * 32 + p * 16) * 32], 16, 0, 0);           \
  } while (0)

#define COMPUTE(bi) do {                                                      \
    const __bf16* as_ = As[bi];                                               \
    const __bf16* bs_ = Bs[bi];                                               \
    bf16x8 af[8], bfr[4];                                                     \
    _Pragma("unroll")                                                         \
    for (int i = 0; i < 8; ++i) {                                             \
      int ra = wm + i * 16 + l15;                                             \
      af[i] = *(const bf16x8*)(&as_[ra * 32 + ((quad ^ ((ra >> 1) & 3)) * 8)]);\
    }                                                                         \
    _Pragma("unroll")                                                         \
    for (int j = 0; j < 4; ++j) {                                             \
      int rb = wn + j * 16 + l15;                                             \
      bfr[j] = *(const bf16x8*)(&bs_[rb * 32 + ((quad ^ ((rb >> 1) & 3)) * 8)]);\
    }                                                                         \
    _Pragma("unroll")                                                         \
    for (int i = 0; i < 8; ++i)                                               \
      _Pragma("unroll")                                                       \
      for (int j = 0; j < 4; ++j)                                             \
        acc[i][j] = __builtin_amdgcn_mfma_f32_16x16x32_bf16(                  \
            af[i], bfr[j], acc[i][j], 0, 0, 0);                               \
  } while (0)

#define TILE_BARRIER(vm) do {                                                 \
    asm volatile("s_waitcnt vmcnt(" #vm ")" ::: "memory");                    \
    __builtin_amdgcn_sched_barrier(0);                                        \
    __builtin_amdgcn_s_barrier();                                             \
    __builtin_amdgcn_sched_barrier(0);                                        \
  } while (0)

  floatx4 acc[8][4] = {};

  STAGE(0); STAGE(1); STAGE(2);             // depth-3 prologue (12 loads)

  #pragma unroll 1
  for (int t = 0; t < 29; ++t) {            // steady state: stage t+3
    TILE_BARRIER(8);                        // tile t landed (2 newer in air)
    STAGE(t + 3);
    COMPUTE(t & 3);
  }
  TILE_BARRIER(8); COMPUTE(1);              // t=29 (29&3==1), no stage left
  TILE_BARRIER(4); COMPUTE(2);              // t=30
  TILE_BARRIER(0); COMPUTE(3);              // t=31
#undef STAGE
#undef COMPUTE
#undef TILE_BARRIER

  // epilogue: D[m=quad*4+r][n=l15] per 16x16 tile; add bias
  #pragma unroll
  for (int j = 0; j < 4; ++j) {
    int n = n0 + wn + j * 16 + l15;
    float bv = bias[n];
    #pragma unroll
    for (int i = 0; i < 8; ++i) {
      int mb = m0 + wm + i * 16 + quad * 4;
      #pragma unroll
      for (int r = 0; r < 4; ++r)
        out[(size_t)(mb + r) * 1024 + n] = acc[i][j][r] + bv;
    }
  }
}

// ---------------------------------------------------------------------------
extern "C" void kernel_launch(void* const* d_in, const int* in_sizes, int n_in,
                              void* d_out, int out_size, void* d_ws, size_t ws_size,
                              hipStream_t stream) {
  const float* x    = (const float*)d_in[0];
  const float* mix  = (const float*)d_in[1];
  const float* W    = (const float*)d_in[2];
  const float* bias = (const float*)d_in[3];
  float* out = (float*)d_out;

  __bf16* ev = (__bf16*)d_ws;                                     // 32 MiB
  __bf16* Wb = (__bf16*)((char*)d_ws + (size_t)32 * 1024 * 1024); // 2 MiB

  convert_w<<<dim3((D_DIM * D_DIM / 4) / 256), 256, 0, stream>>>(W, Wb);
  pde_kernel<<<dim3(NTT, D_DIM / 8, 4), 512, 0, stream>>>(x, mix, ev);
  gemm_kernel<<<dim3(16384 / 256, 1024 / 256), 512, 0, stream>>>(ev, Wb, bias, out);
}

// Round 7
// 323.264 us; speedup vs baseline: 5.2594x; 1.0044x over previous
//
#include <hip/hip_runtime.h>
#include <hip/hip_bf16.h>

// ---------------------------------------------------------------------------
// SolitonInteractionLayer: fused PDE (sine-Gordon + KdV + Heimburg-Jackson,
// RK4, 3 steps) along T, then out = evolved @ W^T + b via bf16 MFMA GEMM.
//
// PDE: causal stencils only. Dependence depth = 12 rhs evals * <=4 = 48 ->
// tile T with left halo 48. Thread owns NP=8 contiguous t-points in regs;
// chunk halo moves via __shfl_up within the 64-lane wave (wave = d-column).
// Substep loops iterate i DESCENDING (causal -> safe in-place).
//
// R12: PDE = fp32 (R9, proven 212us). f16 is DEAD for this op: legit
// interior values reach ~±100+ (ref outputs ±568 -> threshold 35.5), and
// HJ's g=(1+u+u^2)*du squares them -> intermediates ~1e5-1e6 > f16 range.
// Both f16 NaNs were legitimate-data overflow, not halo garbage.
//
// VGPR history (do NOT tighten launch_bounds):
//   (256,2) V128 218us | (256,4)/(512,4) V64 212-218us | (512,8) V32 SPILL
//   6.5GB scratch, 1620us. Keep (512,4): cap 128.
//
// GEMM R12: 1-block/CU 8-wave convoy -> 2 blocks/CU. 128x256 tile, 256 thr
// / 4 waves (wave tile 128x64 keeps ds:MFMA ratio), BK=32, THREE 24KB LDS
// buffers (72KB -> 2 blocks/CU resident). STAGE(t+2) right after barrier t
// (buffer's readers = tile t-1, all past barrier). Steady vmcnt(6). Grid
// (128,4)=512 blocks; A-panel sharers 128 apart (128%8==0 -> same XCD L2).
// ---------------------------------------------------------------------------

typedef __bf16 bf16x8 __attribute__((ext_vector_type(8)));
typedef __bf16 bf16x4 __attribute__((ext_vector_type(4)));
typedef float  floatx4 __attribute__((ext_vector_type(4)));

#define T_DIM 4096
#define D_DIM 1024
#define NP    8       // t-points per thread chunk
#define HALO  48      // 6 chunks
#define NCH   64      // chunks per d-column (one 64-lane wave)
#define TINT  (NCH * NP - HALO)   // 464 interior t per block
#define NTT   9       // ceil(4096/464)

__device__ __forceinline__ float sg_rhs(float c, float m1, float m2, float vv) {
  float dxx = fmaf(-2.f, m1, c) + m2;           // u - 2u1 + u2   (C2 = 1)
  return dxx - __sinf(c) - 0.5f * vv;
}
__device__ __forceinline__ float kdv_rhs(float c, float m1, float m2, float m3) {
  float dxu = c - m1;
  float dx3 = fmaf(-3.f, m1, c) + fmaf(3.f, m2, -m3);   // u -3u1 +3u2 -u3
  return fmaf(-6.f * c, dxu, -dx3 - 0.5f * c);
}
// HJ with g-reuse: k = (g[i] - g[i-1]) - dxxxx - 0.5 v
__device__ __forceinline__ float hj_rhs2(float c, float m1, float m2, float m3,
                                         float m4, float dg, float vv) {
  float d4 = fmaf(-4.f, m3, fmaf(6.f, m2, fmaf(-4.f, m1, c))) + m4;  // dxxxx
  return (dg - d4) - 0.5f * vv;
}
__device__ __forceinline__ float hj_g(float c, float m1) {
  return (fmaf(c, c, c) + 1.f) * (c - m1);      // (1+u+u^2)*dx(u)
}

// stencil access with register halo (compile-time idx after unroll):
// i=-1 -> hl[3], -2 -> hl[2], -3 -> hl[1], -4 -> hl[0]
#define AT(F, i) (((i) >= 0) ? F[(i)] : hl[4 + (i)])
// pull neighbor chunk's top values (lane tr-1). tr==0 self-receives:
// contamination advances <= depth per eval; per-solver totals (12 evals x
// depth: SG 24, KdV 36, HJ 48) all <= HALO=48 -> interior (tr>=6) exact.
#define XCHG4(F) do { \
    hl[0] = __shfl_up(F[NP - 4], 1, 64); \
    hl[1] = __shfl_up(F[NP - 3], 1, 64); \
    hl[2] = __shfl_up(F[NP - 2], 1, 64); \
    hl[3] = __shfl_up(F[NP - 1], 1, 64); \
  } while (0)
#define XCHG3(F) do { \
    hl[1] = __shfl_up(F[NP - 3], 1, 64); \
    hl[2] = __shfl_up(F[NP - 2], 1, 64); \
    hl[3] = __shfl_up(F[NP - 1], 1, 64); \
  } while (0)
#define XCHG2(F) do { \
    hl[2] = __shfl_up(F[NP - 2], 1, 64); \
    hl[3] = __shfl_up(F[NP - 1], 1, 64); \
  } while (0)

__global__ __launch_bounds__(512, 4)
void pde_kernel(const float* __restrict__ x, const float* __restrict__ mix,
                __bf16* __restrict__ evout) {
  const int tid  = threadIdx.x;
  const int tr   = tid & 63;       // chunk index within d-column (= lane)
  const int wid  = tid >> 6;       // 0..7 = d-column (one wave each)
  const int d    = blockIdx.y * 8 + wid;
  const int b    = blockIdx.z;
  const int t0   = blockIdx.x * TINT;
  const int tb   = t0 - HALO + tr * NP;   // t of reg[0]

  // softmax(solver_mix) per-thread (3 elements)
  float s0 = mix[0], s1 = mix[1], s2 = mix[2];
  float mxv = fmaxf(s0, fmaxf(s1, s2));
  float e0 = __expf(s0 - mxv), e1 = __expf(s1 - mxv), e2 = __expf(s2 - mxv);
  float inv = 1.f / (e0 + e1 + e2);
  float w0 = e0 * inv, w1 = e1 * inv, w2 = e2 * inv;

  const float* xp = x + ((size_t)b * T_DIM) * D_DIM + d;

  float u0[NP], u[NP], v[NP], ut[NP], vt[NP], au[NP], av[NP], ev[NP], hl[4];

  #pragma unroll
  for (int j = 0; j < NP; ++j) {
    int t = tb + j;
    float xv = (t >= 0 && t < T_DIM) ? xp[(size_t)t * D_DIM] : 0.f;
    // fast tanh: 2*tanh(x) = 2 - 4/(e^{2x}+1); clamp avoids inf/inf
    float xc = fminf(fmaxf(xv, -9.f), 9.f);
    float ex = __expf(2.f * xc);
    u0[j] = 2.f - 4.f * __builtin_amdgcn_rcpf(ex + 1.f);
  }

  // ---------------- sine-Gordon (2nd order, dt = 0.05) ----------------
  {
    const float dt = 0.05f, h = 0.025f, w6 = dt * (1.f / 6.f);
    #pragma unroll
    for (int j = 0; j < NP; ++j) { u[j] = u0[j]; v[j] = 0.f; }
    #pragma unroll 1
    for (int s = 0; s < 3; ++s) {
      XCHG2(u);
      #pragma unroll
      for (int i = NP - 1; i >= 0; --i) {            // k1
        float k = sg_rhs(u[i], AT(u, i - 1), AT(u, i - 2), v[i]);
        au[i] = v[i]; av[i] = k;
        ut[i] = fmaf(h, v[i], u[i]);
        vt[i] = fmaf(h, k, v[i]);
      }
      XCHG2(ut);
      #pragma unroll
      for (int i = NP - 1; i >= 0; --i) {            // k2
        float k = sg_rhs(ut[i], AT(ut, i - 1), AT(ut, i - 2), vt[i]);
        au[i] = fmaf(2.f, vt[i], au[i]); av[i] = fmaf(2.f, k, av[i]);
        float nu = fmaf(h, vt[i], u[i]);             // u + h*k2u (k2u = old vt)
        vt[i] = fmaf(h, k, v[i]);
        ut[i] = nu;
      }
      XCHG2(ut);
      #pragma unroll
      for (int i = NP - 1; i >= 0; --i) {            // k3
        float k = sg_rhs(ut[i], AT(ut, i - 1), AT(ut, i - 2), vt[i]);
        au[i] = fmaf(2.f, vt[i], au[i]); av[i] = fmaf(2.f, k, av[i]);
        float nu = fmaf(dt, vt[i], u[i]);
        vt[i] = fmaf(dt, k, v[i]);
        ut[i] = nu;
      }
      XCHG2(ut);
      #pragma unroll
      for (int i = NP - 1; i >= 0; --i) {            // k4 + combine
        float k = sg_rhs(ut[i], AT(ut, i - 1), AT(ut, i - 2), vt[i]);
        au[i] += vt[i]; av[i] += k;
        u[i] = fmaf(w6, au[i], u[i]);
        v[i] = fmaf(w6, av[i], v[i]);
      }
    }
    #pragma unroll
    for (int j = 0; j < NP; ++j) ev[j] = w0 * u[j];
  }

  // ---------------- KdV (1st order, dt = 0.025) ----------------
  {
    const float dt = 0.025f, h = 0.0125f, w6 = dt * (1.f / 6.f);
    #pragma unroll
    for (int j = 0; j < NP; ++j) u[j] = u0[j];
    #pragma unroll 1
    for (int s = 0; s < 3; ++s) {
      XCHG3(u);
      #pragma unroll
      for (int i = NP - 1; i >= 0; --i) {            // k1
        float k = kdv_rhs(u[i], AT(u, i - 1), AT(u, i - 2), AT(u, i - 3));
        au[i] = k;
        ut[i] = fmaf(h, k, u[i]);
      }
      XCHG3(ut);
      #pragma unroll
      for (int i = NP - 1; i >= 0; --i) {            // k2
        float k = kdv_rhs(ut[i], AT(ut, i - 1), AT(ut, i - 2), AT(ut, i - 3));
        au[i] = fmaf(2.f, k, au[i]);
        ut[i] = fmaf(h, k, u[i]);
      }
      XCHG3(ut);
      #pragma unroll
      for (int i = NP - 1; i >= 0; --i) {            // k3
        float k = kdv_rhs(ut[i], AT(ut, i - 1), AT(ut, i - 2), AT(ut, i - 3));
        au[i] = fmaf(2.f, k, au[i]);
        ut[i] = fmaf(dt, k, u[i]);
      }
      XCHG3(ut);
      #pragma unroll
      for (int i = NP - 1; i >= 0; --i) {            // k4 + combine
        float k = kdv_rhs(ut[i], AT(ut, i - 1), AT(ut, i - 2), AT(ut, i - 3));
        u[i] = fmaf(w6, au[i] + k, u[i]);
      }
    }
    #pragma unroll
    for (int j = 0; j < NP; ++j) ev[j] = fmaf(w1, u[j], ev[j]);
  }

  // ---------------- Heimburg-Jackson (2nd order, dt = 0.025) ----------------
  {
    const float dt = 0.025f, h = 0.0125f, w6 = dt * (1.f / 6.f);
    float g[NP], gB;
    // per-substep: XCHG4(SRC); precompute g[] (old values); then descending
    // in-place update. g uses only SRC[i], SRC[i-1] -> safe before update.
#define HJ_GPRE(SRC) do {                                                  \
      gB = hj_g(hl[3], hl[2]);                                             \
      _Pragma("unroll")                                                    \
      for (int i_ = 0; i_ < NP; ++i_)                                      \
        g[i_] = hj_g(SRC[i_], AT(SRC, i_ - 1));                           \
    } while (0)
#define DG(i) ((i) ? (g[(i) - 1]) : gB)

    #pragma unroll
    for (int j = 0; j < NP; ++j) { u[j] = u0[j]; v[j] = 0.f; }
    #pragma unroll 1
    for (int s = 0; s < 3; ++s) {
      XCHG4(u);
      HJ_GPRE(u);
      #pragma unroll
      for (int i = NP - 1; i >= 0; --i) {            // k1
        float k = hj_rhs2(u[i], AT(u, i - 1), AT(u, i - 2), AT(u, i - 3),
                          AT(u, i - 4), g[i] - DG(i), v[i]);
        au[i] = v[i]; av[i] = k;
        ut[i] = fmaf(h, v[i], u[i]);
        vt[i] = fmaf(h, k, v[i]);
      }
      XCHG4(ut);
      HJ_GPRE(ut);
      #pragma unroll
      for (int i = NP - 1; i >= 0; --i) {            // k2
        float k = hj_rhs2(ut[i], AT(ut, i - 1), AT(ut, i - 2), AT(ut, i - 3),
                          AT(ut, i - 4), g[i] - DG(i), vt[i]);
        au[i] = fmaf(2.f, vt[i], au[i]); av[i] = fmaf(2.f, k, av[i]);
        float nu = fmaf(h, vt[i], u[i]);
        vt[i] = fmaf(h, k, v[i]);
        ut[i] = nu;
      }
      XCHG4(ut);
      HJ_GPRE(ut);
      #pragma unroll
      for (int i = NP - 1; i >= 0; --i) {            // k3
        float k = hj_rhs2(ut[i], AT(ut, i - 1), AT(ut, i - 2), AT(ut, i - 3),
                          AT(ut, i - 4), g[i] - DG(i), vt[i]);
        au[i] = fmaf(2.f, vt[i], au[i]); av[i] = fmaf(2.f, k, av[i]);
        float nu = fmaf(dt, vt[i], u[i]);
        vt[i] = fmaf(dt, k, v[i]);
        ut[i] = nu;
      }
      XCHG4(ut);
      HJ_GPRE(ut);
      #pragma unroll
      for (int i = NP - 1; i >= 0; --i) {            // k4 + combine
        float k = hj_rhs2(ut[i], AT(ut, i - 1), AT(ut, i - 2), AT(ut, i - 3),
                          AT(ut, i - 4), g[i] - DG(i), vt[i]);
        au[i] += vt[i]; av[i] += k;
        u[i] = fmaf(w6, au[i], u[i]);
        v[i] = fmaf(w6, av[i], v[i]);
      }
    }
#undef HJ_GPRE
#undef DG
    #pragma unroll
    for (int j = 0; j < NP; ++j) ev[j] = fmaf(w2, u[j], ev[j]);
  }

  // store interior chunks (tr >= HALO/NP) as bf16 A-matrix [b*T+t][d]
  if (tr >= HALO / NP) {
    #pragma unroll
    for (int j = 0; j < NP; ++j) {
      int t = tb + j;
      if (t < T_DIM)
        evout[((size_t)(b * T_DIM + t)) * D_DIM + d] = (__bf16)ev[j];
    }
  }
}

// ---------------------------------------------------------------------------
// W (fp32, [E][D]) -> bf16
// ---------------------------------------------------------------------------
__global__ __launch_bounds__(256)
void convert_w(const float* __restrict__ W, __bf16* __restrict__ Wb) {
  int i = blockIdx.x * 256 + threadIdx.x;   // over D*D/4
  float4 f = ((const float4*)W)[i];
  bf16x4 o = {(__bf16)f.x, (__bf16)f.y, (__bf16)f.z, (__bf16)f.w};
  ((bf16x4*)Wb)[i] = o;
}

// ---------------------------------------------------------------------------
// GEMM: out[m][n] = sum_k A[m][k] * Wb[n][k] + bias[n]
// M=16384, N=1024, K=1024.
//
// R12: 128x256 block tile, BK=32, 256 threads / 4 waves (wave tile 128x64,
// acc[8][4]), mfma_f32_16x16x32_bf16. THREE LDS buffers (3 x 24KB = 72KB)
// -> 2 blocks/CU resident (grid 512 = 2/CU): when one block stalls on its
// tile barrier, the other block's waves keep the MFMA pipe fed (the 8-wave
// single-block convoy had nothing to overlap with). Depth-2 prefetch:
// STAGE(t+2) right after barrier t (target buffer's readers = tile t-1,
// all waves past barrier t -> done). Steady vmcnt(6) (= tile t+1's 6 loads
// in flight). Tail: vmcnt(6), vmcnt(0). LDS swizzle: granule g of row r at
// slot g ^ ((r>>1)&3); inverse on global source (both-sides-or-neither).
// A-panel sharers (same bx, 4 by) are 128 apart in dispatch id; 128%8==0
// -> same XCD -> A panels L2-shared (A fetch stays ~32MB).
// ---------------------------------------------------------------------------
#define GK   1024

__global__ __launch_bounds__(256, 2)
void gemm_kernel(const __bf16* __restrict__ A, const __bf16* __restrict__ Bw,
                 const float* __restrict__ bias, float* __restrict__ out) {
  __shared__ __align__(16) __bf16 As[3][128 * 32];   // 3 x 8 KB
  __shared__ __align__(16) __bf16 Bs[3][256 * 32];   // 3 x 16 KB

  const int tid  = threadIdx.x;
  const int lane = tid & 63;
  const int wid  = tid >> 6;           // 0..3
  const int m0   = blockIdx.x * 128;
  const int n0   = blockIdx.y * 256;
  const int wn   = wid * 64;           // wave tile: rows 0..127, cols wn..wn+63
  const int l15  = lane & 15;
  const int quad = lane >> 4;          // K-granule 0..3 (K=32 = 4 x 8 elems)

  // staging: one global_load_lds = 64 lanes x 16B = 16 rows x 64B.
  // lane -> LDS (row = lane>>2, slot = lane&3); must FETCH global granule
  // slot ^ ((row>>1)&3)  (inverse of the read-side swizzle).
  const int srow = lane >> 2;                      // 0..15
  const int sgr  = (lane & 3) ^ ((lane >> 3) & 3); // swizzled global granule

  // wave w stages A rows [w*32, w*32+32) (2 loads), B rows [w*64, w*64+64)
  // (4 loads) -> 6 loads/wave/tile.
  const __bf16* aBase = A  + (size_t)(m0 + wid * 32 + srow) * GK + sgr * 8;
  const __bf16* bBase = Bw + (size_t)(n0 + wid * 64 + srow) * GK + sgr * 8;

#define STAGE(tt, bf) do {                                                    \
    int _kt = (tt) * 32;                                                      \
    _Pragma("unroll")                                                         \
    for (int p = 0; p < 2; ++p)                                               \
      __builtin_amdgcn_global_load_lds(                                       \
          (const uint32_t*)(aBase + (size_t)(p * 16) * GK + _kt),             \
          (uint32_t*)&As[bf][(wid * 32 + p * 16) * 32], 16, 0, 0);            \
    _Pragma("unroll")                                                         \
    for (int p = 0; p < 4; ++p)                                               \
      __builtin_amdgcn_global_load_lds(                                       \
          (const uint32_t*)(bBase + (size_t)(p * 16) * GK + _kt),             \
          (uint32_t*)&Bs[bf][(wid * 64 + p * 16) * 32], 16, 0, 0);            \
  } while (0)

#define COMPUTE(bi) do {                                                      \
    const __bf16* as_ = As[bi];                                               \
    const __bf16* bs_ = Bs[bi];                                               \
    bf16x8 af[8], bfr[4];                                                     \
    _Pragma("unroll")                                                         \
    for (int i = 0; i < 8; ++i) {                                             \
      int ra = i * 16 + l15;                                                  \
      af[i] = *(const bf16x8*)(&as_[ra * 32 + ((quad ^ ((ra >> 1) & 3)) * 8)]);\
    }                                                                         \
    _Pragma("unroll")                                                         \
    for (int j = 0; j < 4; ++j) {                                             \
      int rb = wn + j * 16 + l15;                                             \
      bfr[j] = *(const bf16x8*)(&bs_[rb * 32 + ((quad ^ ((rb >> 1) & 3)) * 8)]);\
    }                                                                         \
    _Pragma("unroll")                                                         \
    for (int i = 0; i < 8; ++i)                                               \
      _Pragma("unroll")                                                       \
      for (int j = 0; j < 4; ++j)                                             \
        acc[i][j] = __builtin_amdgcn_mfma_f32_16x16x32_bf16(                  \
            af[i], bfr[j], acc[i][j], 0, 0, 0);                               \
  } while (0)

#define TILE_BARRIER(vm) do {                                                 \
    asm volatile("s_waitcnt vmcnt(" #vm ")" ::: "memory");                    \
    __builtin_amdgcn_sched_barrier(0);                                        \
    __builtin_amdgcn_s_barrier();                                             \
    __builtin_amdgcn_sched_barrier(0);                                        \
  } while (0)

  floatx4 acc[8][4] = {};

  STAGE(0, 0); STAGE(1, 1);                 // depth-2 prologue (12 loads)

  #pragma unroll 1
  for (int t = 0; t < 30; t += 3) {         // tiles t..t+2, static buf ids
    TILE_BARRIER(6); STAGE(t + 2, 2); COMPUTE(0);
    TILE_BARRIER(6); STAGE(t + 3, 0); COMPUTE(1);
    TILE_BARRIER(6); STAGE(t + 4, 1); COMPUTE(2);
  }
  // covers tiles 0..29, stages through tile 31 (t=27 body stages 29,30,31)
  TILE_BARRIER(6); COMPUTE(0);              // tile 30 (buf 30%3=0)
  TILE_BARRIER(0); COMPUTE(1);              // tile 31 (buf 1), full drain
#undef STAGE
#undef COMPUTE
#undef TILE_BARRIER

  // epilogue: D[m=quad*4+r][n=l15] per 16x16 tile; add bias
  #pragma unroll
  for (int j = 0; j < 4; ++j) {
    int n = n0 + wn + j * 16 + l15;
    float bv = bias[n];
    #pragma unroll
    for (int i = 0; i < 8; ++i) {
      int mb = m0 + i * 16 + quad * 4;
      #pragma unroll
      for (int r = 0; r < 4; ++r)
        out[(size_t)(mb + r) * 1024 + n] = acc[i][j][r] + bv;
    }
  }
}

// ---------------------------------------------------------------------------
extern "C" void kernel_launch(void* const* d_in, const int* in_sizes, int n_in,
                              void* d_out, int out_size, void* d_ws, size_t ws_size,
                              hipStream_t stream) {
  const float* x    = (const float*)d_in[0];
  const float* mix  = (const float*)d_in[1];
  const float* W    = (const float*)d_in[2];
  const float* bias = (const float*)d_in[3];
  float* out = (float*)d_out;

  __bf16* ev = (__bf16*)d_ws;                                     // 32 MiB
  __bf16* Wb = (__bf16*)((char*)d_ws + (size_t)32 * 1024 * 1024); // 2 MiB

  convert_w<<<dim3((D_DIM * D_DIM / 4) / 256), 256, 0, stream>>>(W, Wb);
  pde_kernel<<<dim3(NTT, D_DIM / 8, 4), 512, 0, stream>>>(x, mix, ev);
  gemm_kernel<<<dim3(16384 / 128, 1024 / 256), 256, 0, stream>>>(ev, Wb, bias, out);
}